// Round 8
// baseline (276.185 us; speedup 1.0000x reference)
//
#include <hip/hip_runtime.h>
#include <stdint.h>

// HashedEmbeddingBag: out[b][d] = sum_{i<50} weight[(idx[b][i]*P1 + d*P2) % WS]
// WS = 2,000,000; B = 16384; L = 50; D = 128.
//
// R17: R16 geometry (2 blocks/CU, 8 waves/SIMD -- CONFIRMED latency fix:
// 181->163us, VALU 66->87%) + issue-count surgery. Both pipes now near
// saturation (VALU 87%, DS ~85-90% incl. staging writes), so cut issues:
//  - unroll-2 inner loop (R13's proven body): per 2 elements 1x
//    ds_read2_b32 key-pair + 2 gathers = 3 DS issues (was 4); wave-iters
//    per region E[max64 ceil(N/2)] ~3.2 vs E[max64 N] ~5.3 (-45% loop
//    overhead). Was neutral at 1 blk/CU (nothing saturated); converts now.
//  - routing by difference: accumulate s_all and s_odd only; epilogue
//    out_even = s_all - s_odd. 3 ops/elem routing -> saves 2 VALU/elem.
//    f32 cancellation ~1e-6 relative, invisible under accepted 0.25 bf16
//    absmax (threshold 0.71).
//  - K-space compare: CLr is even -> tag = K&1, and (u < LIM) <=>
//    (K < LIMK), LIMK = 2*(len+rlo) - C2 mod 2^32 (<= ~8M, sentinel
//    0x10000000 still terminates). Gather addr = (K&~1) + CLr. Removes
//    the u=K+CLr add from the loop-control dependence chain.
// Geometry: 512 blocks x 32 bags, 16 pairs, SPT=2, 64KB tile, 62 regions,
// 76.75KB smem -> 2 blocks/CU, __launch_bounds__(1024,8).
// Accuracy: same bf16 RNE table; per-(lane,stream) consumption order
// unchanged (elem0 then elem1); s_all/s_odd reassociation is f32-exact
// class. No races: same barrier structure as R16.

#define WS       2000000
#define EMB_DIM  128
#define BAG_LEN  50
#define BATCH    16384

#define NBLK     512
#define NTHR     1024
#define BPB      32                     // bags per block
#define NPAIR    16                     // bag-pair streams per block
#define SPT      2                      // streams per thread
#define EXTP     204                    // 100 + 100 rotation + 4 sentinels
#define TILEE    32768                  // tile entries (bf16) = 64KB
#define NREGS    62                     // 61*32768=1,998,848; last 1152
#define SBIG     300227u                // P2 % WS
#define SENT     0x10000000u            // sentinel key; never < LIMK

#define OFF_EXT  65536                  // 16*204*4 = 13056 B keys
#define SMEM_SZ  78592                  // 76.75 KB -> 2 blocks/CU

#define GLOAD_LDS16(gp, lp)                                            \
    __builtin_amdgcn_global_load_lds(                                  \
        (const __attribute__((address_space(1))) uint32_t*)(gp),       \
        (__attribute__((address_space(3))) uint32_t*)(lp), 16, 0, 0)

// ---- pre-pass: fp32 table -> bf16 (round-to-nearest-even) ----
__global__ __launch_bounds__(1024) void conv_bf16(
    const float* __restrict__ w, uint16_t* __restrict__ o)
{
    const int i = (blockIdx.x * 1024 + threadIdx.x) * 4;   // 4 floats/thread
    if (i >= WS) return;
    const float4 f = *(const float4*)(w + i);
    uint32_t u0 = __float_as_uint(f.x), u1 = __float_as_uint(f.y);
    uint32_t u2 = __float_as_uint(f.z), u3 = __float_as_uint(f.w);
    ushort4 r;
    r.x = (uint16_t)((u0 + 0x7FFFu + ((u0 >> 16) & 1u)) >> 16);
    r.y = (uint16_t)((u1 + 0x7FFFu + ((u1 >> 16) & 1u)) >> 16);
    r.z = (uint16_t)((u2 + 0x7FFFu + ((u2 >> 16) & 1u)) >> 16);
    r.w = (uint16_t)((u3 + 0x7FFFu + ((u3 >> 16) & 1u)) >> 16);
    *(ushort4*)(o + i) = r;
}

__global__ __launch_bounds__(NTHR, 8) void heb_bf16(
    const uint16_t* __restrict__ wbf,
    const int*      __restrict__ indices,
    float*          __restrict__ out)
{
    __shared__ __align__(16) uint8_t smem[SMEM_SZ];

    const int tid     = threadIdx.x;
    const int d       = tid & 127;
    const int g       = tid >> 7;          // group 0..7 (pairs 2g, 2g+1)
    const int bagBase = blockIdx.x * BPB;

    uint16_t* tile0 = (uint16_t*)&smem[0];
    uint32_t* ext   = (uint32_t*)&smem[OFF_EXT];
    // sort scratch in tile region (dead before region-0 staging, which
    // happens only after the phase-3 barrier)
    uint32_t* araw  = (uint32_t*)&smem[0];        // [32][52] = 6656 B
    uint32_t* S     = (uint32_t*)&smem[6656];     // [32][52]

    // ---- phase 1: sentinel-fill ext; hash a = idx*P1 % WS ----
    for (int p = tid; p < NPAIR * EXTP; p += NTHR) ext[p] = SENT;
    for (int p = tid; p < BPB * BAG_LEN; p += NTHR) {
        uint32_t b = (uint32_t)p / 50u;
        uint32_t i = (uint32_t)p - b * 50u;
        uint64_t idx = (uint64_t)(uint32_t)
            indices[bagBase * BAG_LEN + p];
        araw[b * 52 + i] = (uint32_t)((idx * 9824516537ull) % (uint64_t)WS);
    }
    __syncthreads();

    // ---- phase 2a: rank-sort each bag (ties by index) -> S ----
    for (int p = tid; p < BPB * BAG_LEN; p += NTHR) {
        uint32_t b = (uint32_t)p / 50u;
        uint32_t i = (uint32_t)p - b * 50u;
        uint32_t v = araw[b * 52 + i];
        int rank = 0;
        for (int q = 0; q < BAG_LEN; ++q) {
            uint32_t w = araw[b * 52 + q];
            rank += (w < v || (w == v && q < (int)i)) ? 1 : 0;
        }
        S[b * 52 + rank] = v;
    }
    __syncthreads();

    // ---- phase 2b: 2-way merge per pair via one binary search ----
    for (int p = tid; p < BPB * BAG_LEN; p += NTHR) {
        uint32_t bag = (uint32_t)p / 50u;
        uint32_t i   = (uint32_t)p - bag * 50u;
        uint32_t pr  = bag >> 1, b = bag & 1u;
        uint32_t v = S[bag * 52 + i];
        const uint32_t* T = &S[(bag ^ 1u) * 52];
        uint32_t key = b ? v + 1u : v;         // tie-break by bag id
        int lo = 0, hi = 50;
        while (lo < hi) {                      // ~6 uniform steps
            int mid = (lo + hi) >> 1;
            bool lt = T[mid] < key;
            lo = lt ? mid + 1 : lo;
            hi = lt ? hi : mid;
        }
        uint32_t* eo = ext + pr * EXTP;
        int rk = (int)i + lo;
        eo[rk]       = (v << 1) | b;                    // first copy
        eo[rk + 100] = ((v + (uint32_t)WS) << 1) | b;   // rotation copy
    }
    __syncthreads();                       // ext final; scratch dead

    // ---- phase 3: per-thread 2-stream init (byte-offset state) ----
    const uint32_t c  = ((uint32_t)d * SBIG) % (uint32_t)WS;
    const uint32_t C2 = (uint32_t)(((int)c - WS) * 2);  // 2*(c-WS) mod 2^32
    const uint32_t limit2 = ((uint32_t)WS - c) << 1;    // keys < 2*(WS-c)

    uint32_t kb4[SPT], K4[SPT];
    float    saR[SPT], soR[SPT];
#pragma unroll
    for (int qi = 0; qi < SPT; ++qi) {
        const uint32_t rbase = (uint32_t)(g * SPT + qi) * EXTP;
        int lo = 0, hi = 100;
        while (lo < hi) {
            int mid = (lo + hi) >> 1;
            bool lt = ext[rbase + (uint32_t)mid] < limit2;
            lo = lt ? mid + 1 : lo;
            hi = lt ? hi : mid;
        }
        kb4[qi] = (uint32_t)OFF_EXT + ((rbase + (uint32_t)lo) << 2);
        K4[qi]  = ext[rbase + (uint32_t)lo];
        saR[qi] = 0.0f; soR[qi] = 0.0f;
    }

    // ---- phase 4: region sweep, single 64KB tile, 2 barriers/region ----
    for (int r = 0; r < NREGS; ++r) {
        const int rlo = r * TILEE;
        const int len = (TILEE < WS - rlo) ? TILEE : (WS - rlo);

        __syncthreads();                   // prev region consumed
        for (int s = tid; s < (len >> 3); s += NTHR)
            GLOAD_LDS16(wbf + rlo + (s << 3), tile0 + (s << 3));
        __syncthreads();                   // barrier drains vmcnt

        const uint32_t CLr  = C2 - ((uint32_t)rlo << 1);       // even
        const uint32_t LIMK = ((uint32_t)(len + rlo) << 1) - C2;

#pragma unroll
        for (int qi = 0; qi < SPT; ++qi) {
            uint32_t kb = kb4[qi], K0 = K4[qi];
            float sa = saR[qi], so = soR[qi];
            while (K0 < LIMK) {
                // adjacent key pair: one ds_read2_b32
                const uint32_t K1 = *(const uint32_t*)(smem + kb + 4u);
                const uint32_t K2 = *(const uint32_t*)(smem + kb + 8u);
                // element 0 (unconditionally due)
                const uint32_t a0 = (K0 & ~1u) + CLr;
                const uint32_t raw0 = *(const uint16_t*)(smem + a0);
                // element 1 (predicated; clamp addr to a0 = safe)
                const bool p1 = K1 < LIMK;
                const uint32_t a1 = p1 ? ((K1 & ~1u) + CLr) : a0;
                const uint32_t raw1 = *(const uint16_t*)(smem + a1);
                const float v0 = __uint_as_float(raw0 << 16);
                const float v1 =
                    p1 ? __uint_as_float(raw1 << 16) : 0.0f;
                // routing by difference: all-sum + odd-sum only
                sa += v0;
                sa += v1;
                so += (K0 & 1u) ? v0 : 0.0f;
                so += (K1 & 1u) ? v1 : 0.0f;   // v1 already 0 if !p1
                kb += p1 ? 8u : 4u;
                K0  = p1 ? K2 : K1;
            }
            kb4[qi] = kb; K4[qi] = K0;
            saR[qi] = sa; soR[qi] = so;
        }
    }

    // ---- phase 5: output (bag even = sa - so, bag odd = so) ----
#pragma unroll
    for (int qi = 0; qi < SPT; ++qi) {
        const int bag = (g << 2) + (qi << 1);
        out[(size_t)(bagBase + bag) * EMB_DIM + d]     = saR[qi] - soR[qi];
        out[(size_t)(bagBase + bag + 1) * EMB_DIM + d] = soR[qi];
    }
}

// ---- fallback (ws too small): R7's proven fp32 single-tile kernel ----
#define BAGS_FB  64
#define RSIZE_FB 32768
#define NREG_FB  62
#define EXT_N    104
#define SENT4    0x10000000u

__global__ __launch_bounds__(NTHR, 4) void heb_single(
    const float* __restrict__ weight,
    const int*   __restrict__ indices,
    float*       __restrict__ out)
{
    __shared__ __align__(16) float tile[RSIZE_FB];
    __shared__ uint32_t ext4[BAGS_FB][EXT_N];
    const int tid = threadIdx.x, d = tid & 127, bag_lo = tid >> 7;
    const int bagBase = blockIdx.x * BAGS_FB;
    uint32_t* araw = (uint32_t*)&tile[0];
    for (int p = tid; p < BAGS_FB * BAG_LEN; p += NTHR) {
        uint32_t g = (uint32_t)p / 50u, i = (uint32_t)p - g * 50u;
        uint64_t idx = (uint64_t)(uint32_t)indices[bagBase * BAG_LEN + p];
        araw[g * 52 + i] = (uint32_t)((idx * 9824516537ull) % (uint64_t)WS);
    }
    __syncthreads();
    for (int p = tid; p < BAGS_FB * BAG_LEN; p += NTHR) {
        uint32_t g = (uint32_t)p / 50u, i = (uint32_t)p - g * 50u;
        uint32_t v = araw[g * 52 + i];
        int rank = 0;
        for (int q = 0; q < BAG_LEN; ++q) {
            uint32_t w = araw[g * 52 + q];
            rank += (w < v || (w == v && q < (int)i)) ? 1 : 0;
        }
        ext4[g][rank] = v << 2;
        ext4[g][rank + 50] = (v + (uint32_t)WS) << 2;
    }
    for (int p = tid; p < BAGS_FB * 4; p += NTHR)
        ext4[p >> 2][100 + (p & 3)] = SENT4;
    __syncthreads();
    const uint32_t c = ((uint32_t)d * SBIG) % (uint32_t)WS;
    const uint32_t C4 = (uint32_t)(((int)c - WS) * 4);
    const uint32_t wmc4 = ((uint32_t)WS - c) << 2;
    uint32_t t4[8], h4[8]; float sm[8];
#pragma unroll
    for (int k = 0; k < 8; ++k) {
        const uint32_t* eg = &ext4[(bag_lo << 3) + k][0];
        int nlow = 0;
        for (int q = 0; q < BAG_LEN; ++q) nlow += (eg[q] < wmc4) ? 1 : 0;
        t4[k] = (uint32_t)nlow << 2; h4[k] = eg[nlow] + C4; sm[k] = 0.0f;
    }
    for (int r = 0; r < NREG_FB; ++r) {
        const int lo = r * RSIZE_FB;
        const int len = (RSIZE_FB < WS - lo) ? RSIZE_FB : (WS - lo);
        __syncthreads();
        for (int s = tid; s < (len >> 2); s += NTHR)
            GLOAD_LDS16(weight + lo + (s << 2), &tile[s << 2]);
        __syncthreads();
        const uint32_t lo4 = ((uint32_t)lo) << 2;
        const uint32_t hi4 = (r == NREG_FB - 1) ? (uint32_t)(4 * WS)
                                                : lo4 + ((uint32_t)RSIZE_FB << 2);
        const char* tb = (const char*)&tile[0];
#pragma unroll
        for (int k = 0; k < 8; ++k) {
            const char* eg = (const char*)&ext4[(bag_lo << 3) + k][0];
            uint32_t t_ = t4[k], h_ = h4[k]; float s_ = sm[k];
            while (h_ < hi4) {
                s_ += *(const float*)(tb + (h_ - lo4));
                t_ += 4u;
                h_ = *(const uint32_t*)(eg + t_) + C4;
            }
            t4[k] = t_; h4[k] = h_; sm[k] = s_;
        }
    }
#pragma unroll
    for (int k = 0; k < 8; ++k)
        out[(size_t)(bagBase + (bag_lo << 3) + k) * EMB_DIM + d] = sm[k];
}

extern "C" void kernel_launch(void* const* d_in, const int* in_sizes, int n_in,
                              void* d_out, int out_size, void* d_ws, size_t ws_size,
                              hipStream_t stream)
{
    const float* weight  = (const float*)d_in[0];   // [2,000,000] fp32
    const int*   indices = (const int*)d_in[1];     // [16384*50] int
    float*       out     = (float*)d_out;           // [16384*128] fp32

    if (ws_size >= (size_t)WS * sizeof(uint16_t)) {
        uint16_t* wbf = (uint16_t*)d_ws;
        conv_bf16<<<(WS / 4 + 1023) / 1024, 1024, 0, stream>>>(weight, wbf);
        heb_bf16<<<NBLK, NTHR, 0, stream>>>(wbf, indices, out);
    } else {
        heb_single<<<256, NTHR, 0, stream>>>(weight, indices, out);
    }
}

// Round 9
// 220.034 us; speedup vs baseline: 1.2552x; 1.2552x over previous
//
#include <hip/hip_runtime.h>
#include <stdint.h>

// HashedEmbeddingBag: out[b][d] = sum_{i<50} weight[(idx[b][i]*P1 + d*P2) % WS]
// WS = 2,000,000; B = 16384; L = 50; D = 128.
//
// R18: R16 geometry + unroll-2 with BOTH gather addresses prefetched.
// R17 post-mortem: dur 163->233, VALU 87->55% with VALU-abs DOWN -- a
// latency regression. Mechanism: R17's gather1 consumed K1 loaded in the
// SAME iteration (key RT -> addr -> gather RT serial chain inside one
// iteration). R16 was software-pipelined by construction (every gather
// addr from the PREVIOUS iteration's key load; carried chain 1 RT/iter).
// R18 restores the pipeline at unroll-2: carry (K0,K1) = this iteration's
// element keys (loaded last iter); prefetch (K2,K3) at kb+8/kb+12
// (adjacent -> ds_read2_b32) for next iter. Both gather addrs ready at
// loop top; carried LDS chain = 1 key-pair RT per 2 elements (HALF of
// R16's per-element chain). Wave-iters/region-stream E[max ceil(c/2)]~3
// vs E[max c]~5.3.
// Salvaged from R17 (both accuracy-proven there, absmax 0.25):
//  - routing by difference: accumulate s_all, s_odd; even = sa - so in
//    the epilogue (saves 2 VALU/elem).
//  - K-space compare: CLr even -> loop cond K<LIMK, gather addr
//    (K&~1)+CLr; LIMK in (4M,8M], sentinel 0x10000000 never passes.
// Advance-by-1 fallback (p1 false) <= once per region-stream; pair reads
// stay within the 4-sentinel pad (max index lo+3 <= 202 < 204).
// Geometry (R16-proven): 512 blocks x 32 bags, 16 pairs, SPT=2, 64KB
// tile, 62 regions, 76.75KB smem -> 2 blocks/CU, 8 waves/SIMD.

#define WS       2000000
#define EMB_DIM  128
#define BAG_LEN  50
#define BATCH    16384

#define NBLK     512
#define NTHR     1024
#define BPB      32                     // bags per block
#define NPAIR    16                     // bag-pair streams per block
#define SPT      2                      // streams per thread
#define EXTP     204                    // 100 + 100 rotation + 4 sentinels
#define TILEE    32768                  // tile entries (bf16) = 64KB
#define NREGS    62                     // 61*32768=1,998,848; last 1152
#define SBIG     300227u                // P2 % WS
#define SENT     0x10000000u            // sentinel key; never < LIMK

#define OFF_EXT  65536                  // 16*204*4 = 13056 B keys
#define SMEM_SZ  78592                  // 76.75 KB -> 2 blocks/CU

#define GLOAD_LDS16(gp, lp)                                            \
    __builtin_amdgcn_global_load_lds(                                  \
        (const __attribute__((address_space(1))) uint32_t*)(gp),       \
        (__attribute__((address_space(3))) uint32_t*)(lp), 16, 0, 0)

// ---- pre-pass: fp32 table -> bf16 (round-to-nearest-even) ----
__global__ __launch_bounds__(1024) void conv_bf16(
    const float* __restrict__ w, uint16_t* __restrict__ o)
{
    const int i = (blockIdx.x * 1024 + threadIdx.x) * 4;   // 4 floats/thread
    if (i >= WS) return;
    const float4 f = *(const float4*)(w + i);
    uint32_t u0 = __float_as_uint(f.x), u1 = __float_as_uint(f.y);
    uint32_t u2 = __float_as_uint(f.z), u3 = __float_as_uint(f.w);
    ushort4 r;
    r.x = (uint16_t)((u0 + 0x7FFFu + ((u0 >> 16) & 1u)) >> 16);
    r.y = (uint16_t)((u1 + 0x7FFFu + ((u1 >> 16) & 1u)) >> 16);
    r.z = (uint16_t)((u2 + 0x7FFFu + ((u2 >> 16) & 1u)) >> 16);
    r.w = (uint16_t)((u3 + 0x7FFFu + ((u3 >> 16) & 1u)) >> 16);
    *(ushort4*)(o + i) = r;
}

__global__ __launch_bounds__(NTHR, 8) void heb_bf16(
    const uint16_t* __restrict__ wbf,
    const int*      __restrict__ indices,
    float*          __restrict__ out)
{
    __shared__ __align__(16) uint8_t smem[SMEM_SZ];

    const int tid     = threadIdx.x;
    const int d       = tid & 127;
    const int g       = tid >> 7;          // group 0..7 (pairs 2g, 2g+1)
    const int bagBase = blockIdx.x * BPB;

    uint16_t* tile0 = (uint16_t*)&smem[0];
    uint32_t* ext   = (uint32_t*)&smem[OFF_EXT];
    // sort scratch in tile region (dead before region-0 staging, which
    // happens only after the phase-3 barrier)
    uint32_t* araw  = (uint32_t*)&smem[0];        // [32][52] = 6656 B
    uint32_t* S     = (uint32_t*)&smem[6656];     // [32][52]

    // ---- phase 1: sentinel-fill ext; hash a = idx*P1 % WS ----
    for (int p = tid; p < NPAIR * EXTP; p += NTHR) ext[p] = SENT;
    for (int p = tid; p < BPB * BAG_LEN; p += NTHR) {
        uint32_t b = (uint32_t)p / 50u;
        uint32_t i = (uint32_t)p - b * 50u;
        uint64_t idx = (uint64_t)(uint32_t)
            indices[bagBase * BAG_LEN + p];
        araw[b * 52 + i] = (uint32_t)((idx * 9824516537ull) % (uint64_t)WS);
    }
    __syncthreads();

    // ---- phase 2a: rank-sort each bag (ties by index) -> S ----
    for (int p = tid; p < BPB * BAG_LEN; p += NTHR) {
        uint32_t b = (uint32_t)p / 50u;
        uint32_t i = (uint32_t)p - b * 50u;
        uint32_t v = araw[b * 52 + i];
        int rank = 0;
        for (int q = 0; q < BAG_LEN; ++q) {
            uint32_t w = araw[b * 52 + q];
            rank += (w < v || (w == v && q < (int)i)) ? 1 : 0;
        }
        S[b * 52 + rank] = v;
    }
    __syncthreads();

    // ---- phase 2b: 2-way merge per pair via one binary search ----
    for (int p = tid; p < BPB * BAG_LEN; p += NTHR) {
        uint32_t bag = (uint32_t)p / 50u;
        uint32_t i   = (uint32_t)p - bag * 50u;
        uint32_t pr  = bag >> 1, b = bag & 1u;
        uint32_t v = S[bag * 52 + i];
        const uint32_t* T = &S[(bag ^ 1u) * 52];
        uint32_t key = b ? v + 1u : v;         // tie-break by bag id
        int lo = 0, hi = 50;
        while (lo < hi) {                      // ~6 uniform steps
            int mid = (lo + hi) >> 1;
            bool lt = T[mid] < key;
            lo = lt ? mid + 1 : lo;
            hi = lt ? hi : mid;
        }
        uint32_t* eo = ext + pr * EXTP;
        int rk = (int)i + lo;
        eo[rk]       = (v << 1) | b;                    // first copy
        eo[rk + 100] = ((v + (uint32_t)WS) << 1) | b;   // rotation copy
    }
    __syncthreads();                       // ext final; scratch dead

    // ---- phase 3: per-thread 2-stream init (byte-offset state) ----
    const uint32_t c  = ((uint32_t)d * SBIG) % (uint32_t)WS;
    const uint32_t C2 = (uint32_t)(((int)c - WS) * 2);  // 2*(c-WS) mod 2^32
    const uint32_t limit2 = ((uint32_t)WS - c) << 1;    // keys < 2*(WS-c)

    uint32_t kb4[SPT], K0s[SPT], K1s[SPT];
    float    saR[SPT], soR[SPT];
#pragma unroll
    for (int qi = 0; qi < SPT; ++qi) {
        const uint32_t rbase = (uint32_t)(g * SPT + qi) * EXTP;
        int lo = 0, hi = 100;
        while (lo < hi) {
            int mid = (lo + hi) >> 1;
            bool lt = ext[rbase + (uint32_t)mid] < limit2;
            lo = lt ? mid + 1 : lo;
            hi = lt ? hi : mid;
        }
        kb4[qi] = (uint32_t)OFF_EXT + ((rbase + (uint32_t)lo) << 2);
        K0s[qi] = ext[rbase + (uint32_t)lo];
        K1s[qi] = ext[rbase + (uint32_t)lo + 1u];
        saR[qi] = 0.0f; soR[qi] = 0.0f;
    }

    // ---- phase 4: region sweep, single 64KB tile, 2 barriers/region ----
    for (int r = 0; r < NREGS; ++r) {
        const int rlo = r * TILEE;
        const int len = (TILEE < WS - rlo) ? TILEE : (WS - rlo);

        __syncthreads();                   // prev region consumed
        for (int s = tid; s < (len >> 3); s += NTHR)
            GLOAD_LDS16(wbf + rlo + (s << 3), tile0 + (s << 3));
        __syncthreads();                   // barrier drains vmcnt

        const uint32_t CLr  = C2 - ((uint32_t)rlo << 1);       // even
        const uint32_t LIMK = ((uint32_t)(len + rlo) << 1) - C2;

#pragma unroll
        for (int qi = 0; qi < SPT; ++qi) {
            uint32_t kb = kb4[qi], K0 = K0s[qi], K1 = K1s[qi];
            float sa = saR[qi], so = soR[qi];
            while (K0 < LIMK) {
                // prefetch key pair for NEXT iteration (adjacent words
                // -> ds_read2_b32); carried chain = this one RT
                const uint32_t K2 = *(const uint32_t*)(smem + kb + 8u);
                const uint32_t K3 = *(const uint32_t*)(smem + kb + 12u);
                // both gather addrs ready at loop top (K0,K1 from the
                // previous iteration -- the R16 pipeline, kept)
                const uint32_t a0 = (K0 & ~1u) + CLr;
                const uint32_t raw0 = *(const uint16_t*)(smem + a0);
                const bool p1 = K1 < LIMK;
                const uint32_t a1 = p1 ? ((K1 & ~1u) + CLr) : a0;
                const uint32_t raw1 = *(const uint16_t*)(smem + a1);
                const float v0 = __uint_as_float(raw0 << 16);
                const float v1 =
                    p1 ? __uint_as_float(raw1 << 16) : 0.0f;
                // routing by difference (R17-proven accuracy)
                sa += v0;
                sa += v1;
                so += (K0 & 1u) ? v0 : 0.0f;
                so += (K1 & 1u) ? v1 : 0.0f;   // v1 already 0 if !p1
                kb += p1 ? 8u : 4u;
                K0  = p1 ? K2 : K1;
                K1  = p1 ? K3 : K2;
            }
            kb4[qi] = kb; K0s[qi] = K0; K1s[qi] = K1;
            saR[qi] = sa; soR[qi] = so;
        }
    }

    // ---- phase 5: output (bag even = sa - so, bag odd = so) ----
#pragma unroll
    for (int qi = 0; qi < SPT; ++qi) {
        const int bag = (g << 2) + (qi << 1);
        out[(size_t)(bagBase + bag) * EMB_DIM + d]     = saR[qi] - soR[qi];
        out[(size_t)(bagBase + bag + 1) * EMB_DIM + d] = soR[qi];
    }
}

// ---- fallback (ws too small): R7's proven fp32 single-tile kernel ----
#define BAGS_FB  64
#define RSIZE_FB 32768
#define NREG_FB  62
#define EXT_N    104
#define SENT4    0x10000000u

__global__ __launch_bounds__(NTHR, 4) void heb_single(
    const float* __restrict__ weight,
    const int*   __restrict__ indices,
    float*       __restrict__ out)
{
    __shared__ __align__(16) float tile[RSIZE_FB];
    __shared__ uint32_t ext4[BAGS_FB][EXT_N];
    const int tid = threadIdx.x, d = tid & 127, bag_lo = tid >> 7;
    const int bagBase = blockIdx.x * BAGS_FB;
    uint32_t* araw = (uint32_t*)&tile[0];
    for (int p = tid; p < BAGS_FB * BAG_LEN; p += NTHR) {
        uint32_t g = (uint32_t)p / 50u, i = (uint32_t)p - g * 50u;
        uint64_t idx = (uint64_t)(uint32_t)indices[bagBase * BAG_LEN + p];
        araw[g * 52 + i] = (uint32_t)((idx * 9824516537ull) % (uint64_t)WS);
    }
    __syncthreads();
    for (int p = tid; p < BAGS_FB * BAG_LEN; p += NTHR) {
        uint32_t g = (uint32_t)p / 50u, i = (uint32_t)p - g * 50u;
        uint32_t v = araw[g * 52 + i];
        int rank = 0;
        for (int q = 0; q < BAG_LEN; ++q) {
            uint32_t w = araw[g * 52 + q];
            rank += (w < v || (w == v && q < (int)i)) ? 1 : 0;
        }
        ext4[g][rank] = v << 2;
        ext4[g][rank + 50] = (v + (uint32_t)WS) << 2;
    }
    for (int p = tid; p < BAGS_FB * 4; p += NTHR)
        ext4[p >> 2][100 + (p & 3)] = SENT4;
    __syncthreads();
    const uint32_t c = ((uint32_t)d * SBIG) % (uint32_t)WS;
    const uint32_t C4 = (uint32_t)(((int)c - WS) * 4);
    const uint32_t wmc4 = ((uint32_t)WS - c) << 2;
    uint32_t t4[8], h4[8]; float sm[8];
#pragma unroll
    for (int k = 0; k < 8; ++k) {
        const uint32_t* eg = &ext4[(bag_lo << 3) + k][0];
        int nlow = 0;
        for (int q = 0; q < BAG_LEN; ++q) nlow += (eg[q] < wmc4) ? 1 : 0;
        t4[k] = (uint32_t)nlow << 2; h4[k] = eg[nlow] + C4; sm[k] = 0.0f;
    }
    for (int r = 0; r < NREG_FB; ++r) {
        const int lo = r * RSIZE_FB;
        const int len = (RSIZE_FB < WS - lo) ? RSIZE_FB : (WS - lo);
        __syncthreads();
        for (int s = tid; s < (len >> 2); s += NTHR)
            GLOAD_LDS16(weight + lo + (s << 2), &tile[s << 2]);
        __syncthreads();
        const uint32_t lo4 = ((uint32_t)lo) << 2;
        const uint32_t hi4 = (r == NREG_FB - 1) ? (uint32_t)(4 * WS)
                                                : lo4 + ((uint32_t)RSIZE_FB << 2);
        const char* tb = (const char*)&tile[0];
#pragma unroll
        for (int k = 0; k < 8; ++k) {
            const char* eg = (const char*)&ext4[(bag_lo << 3) + k][0];
            uint32_t t_ = t4[k], h_ = h4[k]; float s_ = sm[k];
            while (h_ < hi4) {
                s_ += *(const float*)(tb + (h_ - lo4));
                t_ += 4u;
                h_ = *(const uint32_t*)(eg + t_) + C4;
            }
            t4[k] = t_; h4[k] = h_; sm[k] = s_;
        }
    }
#pragma unroll
    for (int k = 0; k < 8; ++k)
        out[(size_t)(bagBase + (bag_lo << 3) + k) * EMB_DIM + d] = sm[k];
}

extern "C" void kernel_launch(void* const* d_in, const int* in_sizes, int n_in,
                              void* d_out, int out_size, void* d_ws, size_t ws_size,
                              hipStream_t stream)
{
    const float* weight  = (const float*)d_in[0];   // [2,000,000] fp32
    const int*   indices = (const int*)d_in[1];     // [16384*50] int
    float*       out     = (float*)d_out;           // [16384*128] fp32

    if (ws_size >= (size_t)WS * sizeof(uint16_t)) {
        uint16_t* wbf = (uint16_t*)d_ws;
        conv_bf16<<<(WS / 4 + 1023) / 1024, 1024, 0, stream>>>(weight, wbf);
        heb_bf16<<<NBLK, NTHR, 0, stream>>>(wbf, indices, out);
    } else {
        heb_single<<<256, NTHR, 0, stream>>>(weight, indices, out);
    }
}